// Round 4
// baseline (493.008 us; speedup 1.0000x reference)
//
#include <hip/hip_runtime.h>
#include <hip/hip_bf16.h>

#define NTOT (4*256*256)      // 262144 feature rows
#define DIM 384
#define KCL 256               // clusters
#define BM 64                 // rows per block tile
#define BK 32                 // k-step
#define TBS 256               // threads per block
#define GRID_MAIN (NTOT/BM)   // 4096 blocks
#define NT (DIM/BK)           // 12 K-steps
#define EPS 1e-12f

// byte offsets inside one 40 KiB staging buffer (identical to R3)
#define AH_OFF 0              // A hi   : 64 rows x 4 slots x 16B = 4 KiB
#define AL_OFF 4096           // A lo   : 4 KiB
#define BH_OFF 8192           // B hi   : 256 rows x 4 slots x 16B = 16 KiB
#define BL_OFF 24576          // B lo   : 16 KiB
#define BUF_BYTES 40960       // two buffers = 81920 B = exactly 160 KiB / 2 blocks

typedef __attribute__((ext_vector_type(8)))  _Float16 f16x8;
typedef __attribute__((ext_vector_type(16))) float    f32x16;

__device__ __forceinline__ void async_copy16(const void* gptr, void* lptr) {
    __builtin_amdgcn_global_load_lds(
        (const __attribute__((address_space(1))) unsigned int*)gptr,
        (__attribute__((address_space(3))) unsigned int*)lptr, 16, 0, 0);
}

// ---------------------------------------------------------------------------
// Pre-pass: L2-normalize cluster centers, emit fp16 hi/lo splits in [n][k]
// ---------------------------------------------------------------------------
__global__ void prep_clusters(const float* __restrict__ cc,
                              _Float16* __restrict__ bh, _Float16* __restrict__ bl) {
    int j = blockIdx.x, l = threadIdx.x;   // 256 blocks x 64 lanes
    float v[6]; float ssq = 0.f;
#pragma unroll
    for (int i = 0; i < 6; ++i) { v[i] = cc[j*DIM + l + 64*i]; ssq = fmaf(v[i], v[i], ssq); }
#pragma unroll
    for (int off = 32; off >= 1; off >>= 1) ssq += __shfl_xor(ssq, off);
    float inv = 1.f / fmaxf(sqrtf(ssq), EPS);
#pragma unroll
    for (int i = 0; i < 6; ++i) {
        float x = v[i] * inv;
        _Float16 h  = (_Float16)x;
        _Float16 lo = (_Float16)(x - (float)h);
        bh[j*DIM + l + 64*i] = h;
        bl[j*DIM + l + 64*i] = lo;
    }
}

// ---------------------------------------------------------------------------
// Main: split-fp16 32x32x16 MFMA GEMM, double-buffered, depth-2 A prefetch,
// counted-vmcnt barriers. LDS chunk (row,g) -> slot row*4 + (g ^ ((row>>1)&3)).
// ---------------------------------------------------------------------------
__global__ __launch_bounds__(TBS)
void kmeans_main(const float* __restrict__ A,    // features [NTOT][384] f32
                 const float* __restrict__ W,    // weight   [NTOT]
                 const _Float16* __restrict__ Bh,// [256][384] fp16 hi
                 const _Float16* __restrict__ Bl,// [256][384] fp16 lo
                 const int*   __restrict__ PA,   // [256]
                 float* __restrict__ out,        // [2*NTOT+1]
                 float* __restrict__ partial)    // [GRID_MAIN]
{
    __shared__ unsigned char smem[2 * BUF_BYTES];

    const int tid  = threadIdx.x;
    const int wv   = tid >> 6;        // wave 0..3 -> cols [64*wv, 64*wv+64)
    const int lane = tid & 63;
    const int l31  = lane & 31;
    const int hi   = lane >> 5;
    const int sw   = (l31 >> 1) & 3;  // read-side swizzle term
    const int row0 = blockIdx.x * BM;
    const int arow = tid >> 2, achk = tid & 3;        // A loader mapping
    const int bg   = (tid & 3) ^ ((tid >> 3) & 3);    // B stage chunk index
    const int awb  = (((arow << 2) + (achk ^ ((arow >> 1) & 3))) << 4);

    const float* aptr = A + (size_t)(row0 + arow) * DIM + achk * 8;

    f32x16 acc[2][2];
#pragma unroll
    for (int m = 0; m < 2; ++m)
#pragma unroll
        for (int n = 0; n < 2; ++n)
#pragma unroll
            for (int j = 0; j < 16; ++j) acc[m][n][j] = 0.f;
    float ssq = 0.f;

    auto stageB = [&](int ks, unsigned char* buf) {
#pragma unroll
        for (int i = 0; i < 4; ++i) {
            int row = i * 64 + (tid >> 2);
            async_copy16(Bh + (size_t)row * DIM + ks + 8 * bg,
                         buf + BH_OFF + ((i * 256 + tid) << 4));
            async_copy16(Bl + (size_t)row * DIM + ks + 8 * bg,
                         buf + BL_OFF + ((i * 256 + tid) << 4));
        }
    };
    auto writeA = [&](const float4& x0, const float4& x1, unsigned char* buf) {
        float av[8] = {x0.x, x0.y, x0.z, x0.w, x1.x, x1.y, x1.z, x1.w};
        f16x8 h8, l8;
#pragma unroll
        for (int w = 0; w < 8; ++w) {
            _Float16 hh = (_Float16)av[w];
            h8[w] = hh;
            l8[w] = (_Float16)(av[w] - (float)hh);
            ssq = fmaf(av[w], av[w], ssq);
        }
        *(f16x8*)(buf + AH_OFF + awb) = h8;
        *(f16x8*)(buf + AL_OFF + awb) = l8;
    };
    auto compute = [&](const unsigned char* buf) {
        f16x8 ahf[2][2], alf[2][2], bhf[2][2], blf[2][2];
#pragma unroll
        for (int m = 0; m < 2; ++m)
#pragma unroll
            for (int kh = 0; kh < 2; ++kh) {
                int ro = (32 * m + l31) * 64 + ((((hi + 2 * kh)) ^ sw) << 4);
                ahf[m][kh] = *(const f16x8*)(buf + AH_OFF + ro);
                alf[m][kh] = *(const f16x8*)(buf + AL_OFF + ro);
            }
#pragma unroll
        for (int n = 0; n < 2; ++n)
#pragma unroll
            for (int kh = 0; kh < 2; ++kh) {
                int ro = wv * 4096 + (32 * n + l31) * 64 + ((((hi + 2 * kh)) ^ sw) << 4);
                bhf[n][kh] = *(const f16x8*)(buf + BH_OFF + ro);
                blf[n][kh] = *(const f16x8*)(buf + BL_OFF + ro);
            }
        __builtin_amdgcn_s_setprio(1);
#pragma unroll
        for (int m = 0; m < 2; ++m)
#pragma unroll
            for (int n = 0; n < 2; ++n)
#pragma unroll
                for (int kh = 0; kh < 2; ++kh)
                    acc[m][n] = __builtin_amdgcn_mfma_f32_32x32x16_f16(ahf[m][kh], bhf[n][kh], acc[m][n], 0, 0, 0);
#pragma unroll
        for (int m = 0; m < 2; ++m)
#pragma unroll
            for (int n = 0; n < 2; ++n)
#pragma unroll
                for (int kh = 0; kh < 2; ++kh)
                    acc[m][n] = __builtin_amdgcn_mfma_f32_32x32x16_f16(ahf[m][kh], blf[n][kh], acc[m][n], 0, 0, 0);
#pragma unroll
        for (int m = 0; m < 2; ++m)
#pragma unroll
            for (int n = 0; n < 2; ++n)
#pragma unroll
                for (int kh = 0; kh < 2; ++kh)
                    acc[m][n] = __builtin_amdgcn_mfma_f32_32x32x16_f16(alf[m][kh], bhf[n][kh], acc[m][n], 0, 0, 0);
        __builtin_amdgcn_s_setprio(0);
    };

    float4 rt0[2], rt1[2];   // A-prefetch slots: rt0 = even tiles, rt1 = odd tiles

    // ---- prologue: load A0, stage tile0, load A1, write A0, counted barrier ----
    rt0[0] = *(const float4*)(aptr);
    rt0[1] = *(const float4*)(aptr + 4);
    stageB(0, smem);
    rt1[0] = *(const float4*)(aptr + BK);
    rt1[1] = *(const float4*)(aptr + BK + 4);
    writeA(rt0[0], rt0[1], smem);
    asm volatile("s_waitcnt vmcnt(2) lgkmcnt(0)" ::: "memory");
    __builtin_amdgcn_s_barrier();

    // ---- main loop, unrolled x2 (static buffer/reg-slot selection) ----
    for (int t = 0; t < NT; t += 2) {
        {   // even step t: compute buf0, stage t+1 -> buf1, consume rt1, load rt0(t+2)
            stageB((t + 1) * BK, smem + BUF_BYTES);
            if (t + 2 < NT) {
                rt0[0] = *(const float4*)(aptr + (t + 2) * BK);
                rt0[1] = *(const float4*)(aptr + (t + 2) * BK + 4);
            }
            compute(smem);
            writeA(rt1[0], rt1[1], smem + BUF_BYTES);
            if (t + 2 < NT) asm volatile("s_waitcnt vmcnt(2) lgkmcnt(0)" ::: "memory");
            else            asm volatile("s_waitcnt vmcnt(0) lgkmcnt(0)" ::: "memory");
            __builtin_amdgcn_s_barrier();
        }
        {   // odd step t+1: compute buf1; stage t+2 -> buf0, consume rt0, load rt1(t+3)
            if (t + 2 < NT) {
                stageB((t + 2) * BK, smem);
                if (t + 3 < NT) {
                    rt1[0] = *(const float4*)(aptr + (t + 3) * BK);
                    rt1[1] = *(const float4*)(aptr + (t + 3) * BK + 4);
                }
                compute(smem + BUF_BYTES);
                writeA(rt0[0], rt0[1], smem);
                if (t + 3 < NT) asm volatile("s_waitcnt vmcnt(2) lgkmcnt(0)" ::: "memory");
                else            asm volatile("s_waitcnt vmcnt(0) lgkmcnt(0)" ::: "memory");
                __builtin_amdgcn_s_barrier();
            } else {
                compute(smem + BUF_BYTES);   // last tile, no restage
            }
        }
    }

    // ---- epilogue (overlay scratch on buf0; buf0 reads finished 2 steps ago) ----
    float* rowssq = (float*)smem;                 // 256 B
    float* wvalp  = (float*)(smem + 256);         // 1 KiB
    int*   wcolp  = (int*)(smem + 1280);          // 1 KiB

    ssq += __shfl_xor(ssq, 1);
    ssq += __shfl_xor(ssq, 2);
    if (achk == 0) rowssq[arow] = ssq;

    // per-row argmax. acc[m][n][j] = S[32m + (j&3)+8*(j>>2)+4*hi][64wv + 32n + l31]
#pragma unroll
    for (int m = 0; m < 2; ++m) {
#pragma unroll
        for (int j = 0; j < 16; ++j) {
            float best = acc[m][0][j];
            int   bc   = wv * 64 + l31;
            float v1 = acc[m][1][j];
            int   c1 = wv * 64 + 32 + l31;
            if (v1 > best) { best = v1; bc = c1; }
#pragma unroll
            for (int off = 1; off < 32; off <<= 1) {
                float ov = __shfl_xor(best, off);
                int   oc = __shfl_xor(bc, off);
                if (ov > best || (ov == best && oc < bc)) { best = ov; bc = oc; }
            }
            if (l31 == 0) {
                int r = 32 * m + (j & 3) + 8 * (j >> 2) + 4 * hi;
                wvalp[wv * 64 + r] = best;
                wcolp[wv * 64 + r] = bc;
            }
        }
    }
    __syncthreads();

    if (tid < BM) {
        int r = tid;
        float best = wvalp[r]; int bc = wcolp[r];
#pragma unroll
        for (int w = 1; w < 4; ++w) {
            float ov = wvalp[w * BM + r]; int oc = wcolp[w * BM + r];
            if (ov > best || (ov == best && oc < bc)) { best = ov; bc = oc; }
        }
        float inv = 1.f / fmaxf(sqrtf(rowssq[r]), EPS);
        out[row0 + r]        = (float)bc;
        out[NTOT + row0 + r] = (float)PA[bc];
        float lsum = -(best * inv) * W[row0 + r];
#pragma unroll
        for (int off = 32; off >= 1; off >>= 1) lsum += __shfl_xor(lsum, off);
        if (tid == 0) partial[blockIdx.x] = lsum;
    }
}

// ---------------------------------------------------------------------------
// Deterministic final loss reduction: 4096 partials -> mean
// ---------------------------------------------------------------------------
__global__ void loss_reduce(const float* __restrict__ partial, float* __restrict__ out_loss) {
    __shared__ float s[256];
    float v = 0.f;
    for (int i = threadIdx.x; i < GRID_MAIN; i += 256) v += partial[i];
    s[threadIdx.x] = v;
    __syncthreads();
    for (int off = 128; off >= 1; off >>= 1) {
        if ((int)threadIdx.x < off) s[threadIdx.x] += s[threadIdx.x + off];
        __syncthreads();
    }
    if (threadIdx.x == 0) out_loss[0] = s[0] * (1.0f / (float)NTOT);
}

extern "C" void kernel_launch(void* const* d_in, const int* in_sizes, int n_in,
                              void* d_out, int out_size, void* d_ws, size_t ws_size,
                              hipStream_t stream) {
    const float* features = (const float*)d_in[0];
    const float* weight   = (const float*)d_in[1];
    const float* cc       = (const float*)d_in[2];
    const int*   pa       = (const int*)d_in[3];
    float* out = (float*)d_out;

    _Float16* bh = (_Float16*)d_ws;               // 192 KiB
    _Float16* bl = bh + KCL * DIM;                // 192 KiB
    float* partial = (float*)(bl + KCL * DIM);    // 16 KiB

    hipLaunchKernelGGL(prep_clusters, dim3(KCL), dim3(64), 0, stream, cc, bh, bl);
    hipLaunchKernelGGL(kmeans_main, dim3(GRID_MAIN), dim3(TBS), 0, stream,
                       features, weight, bh, bl, pa, out, partial);
    hipLaunchKernelGGL(loss_reduce, dim3(1), dim3(256), 0, stream, partial, out + 2 * NTOT);
}

// Round 5
// 210.951 us; speedup vs baseline: 2.3371x; 2.3371x over previous
//
#include <hip/hip_runtime.h>
#include <hip/hip_bf16.h>

#define NTOT (4*256*256)      // 262144 feature rows
#define DIM 384
#define KCL 256               // clusters
#define BM 64                 // rows per block tile
#define BK 32                 // k-step
#define TBS 256               // threads per block
#define GRID_MAIN (NTOT/BM)   // 4096 blocks
#define NT (DIM/BK)           // 12 K-steps
#define EPS 1e-12f

// byte offsets inside the single 40 KiB staging buffer (R3-identical layout)
#define AH_OFF 0              // A hi   : 64 rows x 4 slots x 16B = 4 KiB
#define AL_OFF 4096           // A lo   : 4 KiB
#define BH_OFF 8192           // B hi   : 256 rows x 4 slots x 16B = 16 KiB
#define BL_OFF 24576          // B lo   : 16 KiB
#define BUF_BYTES 40960       // 4 blocks x 40960 = exactly 160 KiB per CU

typedef __attribute__((ext_vector_type(8))) _Float16 f16x8;
typedef __attribute__((ext_vector_type(4))) float f32x4;

__device__ __forceinline__ void async_copy16(const void* gptr, void* lptr) {
    __builtin_amdgcn_global_load_lds(
        (const __attribute__((address_space(1))) unsigned int*)gptr,
        (__attribute__((address_space(3))) unsigned int*)lptr, 16, 0, 0);
}

// ---------------------------------------------------------------------------
// Pre-pass: L2-normalize cluster centers, emit fp16 hi/lo splits in [n][k]
// ---------------------------------------------------------------------------
__global__ void prep_clusters(const float* __restrict__ cc,
                              _Float16* __restrict__ bh, _Float16* __restrict__ bl) {
    int j = blockIdx.x, l = threadIdx.x;   // 256 blocks x 64 lanes
    float v[6]; float ssq = 0.f;
#pragma unroll
    for (int i = 0; i < 6; ++i) { v[i] = cc[j*DIM + l + 64*i]; ssq = fmaf(v[i], v[i], ssq); }
#pragma unroll
    for (int off = 32; off >= 1; off >>= 1) ssq += __shfl_xor(ssq, off);
    float inv = 1.f / fmaxf(sqrtf(ssq), EPS);
#pragma unroll
    for (int i = 0; i < 6; ++i) {
        float x = v[i] * inv;
        _Float16 h  = (_Float16)x;
        _Float16 lo = (_Float16)(x - (float)h);
        bh[j*DIM + l + 64*i] = h;
        bl[j*DIM + l + 64*i] = lo;
    }
}

// ---------------------------------------------------------------------------
// Main: split-fp16 16x16x32 MFMA GEMM, SINGLE-buffered LDS (4 blocks/CU),
// m97-style two-barrier loop, depth-1 A register prefetch.
// LDS chunk (row,g) -> 16B slot row*4 + (g ^ ((row>>1)&3))  [R3, 0 conflicts]
// ---------------------------------------------------------------------------
__global__ __launch_bounds__(TBS, 4)
void kmeans_main(const float* __restrict__ A,    // features [NTOT][384] f32
                 const float* __restrict__ W,    // weight   [NTOT]
                 const _Float16* __restrict__ Bh,// [256][384] fp16 hi
                 const _Float16* __restrict__ Bl,// [256][384] fp16 lo
                 const int*   __restrict__ PA,   // [256]
                 float* __restrict__ out,        // [2*NTOT+1]
                 float* __restrict__ partial)    // [GRID_MAIN]
{
    __shared__ unsigned char smem[BUF_BYTES];

    const int tid  = threadIdx.x;
    const int wv   = tid >> 6;        // wave 0..3 -> cols [64*wv, 64*wv+64)
    const int lane = tid & 63;
    const int g    = lane >> 4;       // k-group 0..3
    const int l15  = lane & 15;
    const int sw   = (l15 >> 1) & 3;  // read-side swizzle term
    const int row0 = blockIdx.x * BM;
    const int arow = tid >> 2, achk = tid & 3;        // A loader mapping
    const int bg   = (tid & 3) ^ ((tid >> 3) & 3);    // B stage chunk index
    const int awb  = (((arow << 2) + (achk ^ ((arow >> 1) & 3))) << 4);
    const int fa   = l15 * 64 + ((g ^ sw) << 4);      // fragment base (+m*1024)
    const int fb   = wv * 4096 + fa;                  // B fragment base (+n*1024)

    const float* aptr = A + (size_t)(row0 + arow) * DIM + achk * 8;

    f32x4 acc[4][4];
#pragma unroll
    for (int m = 0; m < 4; ++m)
#pragma unroll
        for (int n = 0; n < 4; ++n) acc[m][n] = (f32x4){0.f, 0.f, 0.f, 0.f};
    float ssq = 0.f;

    auto stageB = [&](int ks) {
#pragma unroll
        for (int i = 0; i < 4; ++i) {
            int row = i * 64 + (tid >> 2);
            async_copy16(Bh + (size_t)row * DIM + ks + 8 * bg,
                         smem + BH_OFF + ((i * 256 + tid) << 4));
            async_copy16(Bl + (size_t)row * DIM + ks + 8 * bg,
                         smem + BL_OFF + ((i * 256 + tid) << 4));
        }
    };
    auto writeA = [&](const float4& x0, const float4& x1) {
        float av[8] = {x0.x, x0.y, x0.z, x0.w, x1.x, x1.y, x1.z, x1.w};
        f16x8 h8, l8;
#pragma unroll
        for (int w = 0; w < 8; ++w) {
            _Float16 hh = (_Float16)av[w];
            h8[w] = hh;
            l8[w] = (_Float16)(av[w] - (float)hh);
            ssq = fmaf(av[w], av[w], ssq);
        }
        *(f16x8*)(smem + AH_OFF + awb) = h8;
        *(f16x8*)(smem + AL_OFF + awb) = l8;
    };
    auto compute = [&]() {
        f16x8 ahf[4], alf[4], bhf[4], blf[4];
#pragma unroll
        for (int m = 0; m < 4; ++m) {
            ahf[m] = *(const f16x8*)(smem + AH_OFF + fa + m * 1024);
            alf[m] = *(const f16x8*)(smem + AL_OFF + fa + m * 1024);
        }
#pragma unroll
        for (int n = 0; n < 4; ++n) {
            bhf[n] = *(const f16x8*)(smem + BH_OFF + fb + n * 1024);
            blf[n] = *(const f16x8*)(smem + BL_OFF + fb + n * 1024);
        }
#pragma unroll
        for (int m = 0; m < 4; ++m)
#pragma unroll
            for (int n = 0; n < 4; ++n)
                acc[m][n] = __builtin_amdgcn_mfma_f32_16x16x32_f16(ahf[m], bhf[n], acc[m][n], 0, 0, 0);
#pragma unroll
        for (int m = 0; m < 4; ++m)
#pragma unroll
            for (int n = 0; n < 4; ++n)
                acc[m][n] = __builtin_amdgcn_mfma_f32_16x16x32_f16(ahf[m], blf[n], acc[m][n], 0, 0, 0);
#pragma unroll
        for (int m = 0; m < 4; ++m)
#pragma unroll
            for (int n = 0; n < 4; ++n)
                acc[m][n] = __builtin_amdgcn_mfma_f32_16x16x32_f16(alf[m], bhf[n], acc[m][n], 0, 0, 0);
    };

    // ---- prologue: stage tile 0 ----
    {
        float4 c0 = *(const float4*)(aptr);
        float4 c1 = *(const float4*)(aptr + 4);
        stageB(0);
        writeA(c0, c1);
        __syncthreads();
    }

    // ---- main loop: compute(t) | barrier | stage(t+1) | barrier ----
    for (int t = 0; t < NT - 1; ++t) {
        // issue next A loads early: HBM latency covered by compute(t)
        float4 n0 = *(const float4*)(aptr + (t + 1) * BK);
        float4 n1 = *(const float4*)(aptr + (t + 1) * BK + 4);
        compute();
        __syncthreads();            // all LDS reads of tile t done
        stageB((t + 1) * BK);
        writeA(n0, n1);
        __syncthreads();            // drains gl_lds + ds_write (vmcnt/lgkm 0)
    }
    compute();                      // last tile
    __syncthreads();                // before epilogue overlays smem

    // ---- epilogue (overlay scratch on smem) ----
    float* rowssq = (float*)smem;                 // 256 B
    float* wvalp  = (float*)(smem + 256);         // 1 KiB
    int*   wcolp  = (int*)(smem + 1280);          // 1 KiB

    ssq += __shfl_xor(ssq, 1);
    ssq += __shfl_xor(ssq, 2);
    if (achk == 0) rowssq[arow] = ssq;

    // per-row argmax. acc[m][n][j] = S[16m + 4g + j][64wv + 16n + l15]
#pragma unroll
    for (int m = 0; m < 4; ++m) {
#pragma unroll
        for (int j = 0; j < 4; ++j) {
            float best = acc[m][0][j];
            int   bc   = wv * 64 + l15;
#pragma unroll
            for (int n = 1; n < 4; ++n) {
                float v = acc[m][n][j];
                int   c = wv * 64 + 16 * n + l15;
                if (v > best) { best = v; bc = c; }
            }
#pragma unroll
            for (int off = 1; off < 16; off <<= 1) {
                float ov = __shfl_xor(best, off);
                int   oc = __shfl_xor(bc, off);
                if (ov > best || (ov == best && oc < bc)) { best = ov; bc = oc; }
            }
            if (l15 == 0) {
                wvalp[wv * BM + 16 * m + 4 * g + j] = best;
                wcolp[wv * BM + 16 * m + 4 * g + j] = bc;
            }
        }
    }
    __syncthreads();

    if (tid < BM) {
        int r = tid;
        float best = wvalp[r]; int bc = wcolp[r];
#pragma unroll
        for (int w = 1; w < 4; ++w) {
            float ov = wvalp[w * BM + r]; int oc = wcolp[w * BM + r];
            if (ov > best || (ov == best && oc < bc)) { best = ov; bc = oc; }
        }
        float inv = 1.f / fmaxf(sqrtf(rowssq[r]), EPS);
        out[row0 + r]        = (float)bc;
        out[NTOT + row0 + r] = (float)PA[bc];
        float lsum = -(best * inv) * W[row0 + r];
#pragma unroll
        for (int off = 32; off >= 1; off >>= 1) lsum += __shfl_xor(lsum, off);
        if (tid == 0) partial[blockIdx.x] = lsum;
    }
}

// ---------------------------------------------------------------------------
// Deterministic final loss reduction: 4096 partials -> mean
// ---------------------------------------------------------------------------
__global__ void loss_reduce(const float* __restrict__ partial, float* __restrict__ out_loss) {
    __shared__ float s[256];
    float v = 0.f;
    for (int i = threadIdx.x; i < GRID_MAIN; i += 256) v += partial[i];
    s[threadIdx.x] = v;
    __syncthreads();
    for (int off = 128; off >= 1; off >>= 1) {
        if ((int)threadIdx.x < off) s[threadIdx.x] += s[threadIdx.x + off];
        __syncthreads();
    }
    if (threadIdx.x == 0) out_loss[0] = s[0] * (1.0f / (float)NTOT);
}

extern "C" void kernel_launch(void* const* d_in, const int* in_sizes, int n_in,
                              void* d_out, int out_size, void* d_ws, size_t ws_size,
                              hipStream_t stream) {
    const float* features = (const float*)d_in[0];
    const float* weight   = (const float*)d_in[1];
    const float* cc       = (const float*)d_in[2];
    const int*   pa       = (const int*)d_in[3];
    float* out = (float*)d_out;

    _Float16* bh = (_Float16*)d_ws;               // 192 KiB
    _Float16* bl = bh + KCL * DIM;                // 192 KiB
    float* partial = (float*)(bl + KCL * DIM);    // 16 KiB

    hipLaunchKernelGGL(prep_clusters, dim3(KCL), dim3(64), 0, stream, cc, bh, bl);
    hipLaunchKernelGGL(kmeans_main, dim3(GRID_MAIN), dim3(TBS), 0, stream,
                       features, weight, bh, bl, pa, out, partial);
    hipLaunchKernelGGL(loss_reduce, dim3(1), dim3(256), 0, stream, partial, out + 2 * NTOT);
}